// Round 5
// baseline (269.303 us; speedup 1.0000x reference)
//
#include <hip/hip_runtime.h>
#include <cmath>

// Problem constants (match reference)
#define IN_F   4096
#define OUT_F  1024
#define NBITS  8
#define JTOT   (OUT_F * NBITS)   // 8192 bit-columns
#define TB     256               // threads per block
#define CPT    4                 // columns per thread (float4)
#define JBLK   (TB * CPT)        // 1024 columns per column-block
#define NJB    (JTOT / JBLK)     // 8 column-blocks
#define ROWS   64                // rows per split-K chunk
#define NCHUNK (IN_F / ROWS)     // 64 chunks
#define NEUR_PER_CB (JBLK / NBITS)  // 128 neurons per column-block

typedef float f32x4 __attribute__((ext_vector_type(4)));

// Single fused kernel.
// Phase 1 (all 8x64 blocks): split-K column sums
//   S[j] = sum_i latent[i] * (w[i,j] > 0.5), f32 chunk partials -> ws.
//   w streamed nontemporal (read-once; keeps partials L2-resident).
// Phase 2 (last-arriving block per column-group, threadfence/atomic ticket):
//   reduce 64 chunk partials (f64), exact closed-form ripple-carry
//     T_b = S_b + C_{b-1}; acc_b = T_b mod 2; C_b = floor(T_b/2)
//   trigger[o,b] = acc_b - true_sum; per-group loss partial -> ws.
// Phase 3 (globally last finalizer): out[0] = 0.5/OUT_F * sum lossp (written
//   exactly once -> no output memset needed).
__global__ __launch_bounds__(TB) void fused_kernel(
    const float* __restrict__ w, const float* __restrict__ latent,
    const float* __restrict__ true_sum, float* __restrict__ partials,
    double* __restrict__ lossp, int* __restrict__ ctr,
    int* __restrict__ fin_ctr, float* __restrict__ out) {
  const int x = blockIdx.x;        // column-group 0..7
  const int chunk = blockIdx.y;    // 0..63
  const int tid = threadIdx.x;
  const int j0 = x * JBLK + tid * CPT;
  const int i0 = chunk * ROWS;

  // ---- Phase 1: this block's chunk of the column sums ----
  float a0 = 0.f, a1 = 0.f, a2 = 0.f, a3 = 0.f;
  const f32x4* wp = reinterpret_cast<const f32x4*>(w + (size_t)i0 * JTOT + j0);
#pragma unroll 32
  for (int r = 0; r < ROWS; ++r) {
    const float lat = latent[i0 + r];                 // wave-uniform
    const f32x4 v = __builtin_nontemporal_load(wp + (size_t)r * (JTOT / 4));
    a0 += (v.x > 0.5f) ? lat : 0.0f;
    a1 += (v.y > 0.5f) ? lat : 0.0f;
    a2 += (v.z > 0.5f) ? lat : 0.0f;
    a3 += (v.w > 0.5f) ? lat : 0.0f;
  }
  f32x4 acc = {a0, a1, a2, a3};
  *reinterpret_cast<f32x4*>(partials + (size_t)chunk * JTOT + j0) = acc;

  // ---- ticket: last chunk-block of this column-group finalizes it ----
  __threadfence();                 // release our partials device-wide
  __syncthreads();
  __shared__ int is_last;
  if (tid == 0)
    is_last = (atomicAdd(ctr + x, 1) == NCHUNK - 1) ? 1 : 0;
  __syncthreads();
  if (!is_last) return;
  __threadfence();                 // acquire all groups' partials

  // ---- Phase 2: reduce 64 chunks for this group's 1024 columns (f64) ----
  double s0 = 0.0, s1 = 0.0, s2 = 0.0, s3 = 0.0;
  const float* pp = partials + j0;
#pragma unroll 8
  for (int c = 0; c < NCHUNK; ++c) {
    const f32x4 v = *reinterpret_cast<const f32x4*>(pp + (size_t)c * JTOT);
    s0 += (double)v.x; s1 += (double)v.y; s2 += (double)v.z; s3 += (double)v.w;
  }
  __shared__ double S[JBLK];       // 8 KB
  S[tid * 4 + 0] = s0; S[tid * 4 + 1] = s1;
  S[tid * 4 + 2] = s2; S[tid * 4 + 3] = s3;
  __syncthreads();

  __shared__ double err[NEUR_PER_CB];
  if (tid < NEUR_PER_CB) {         // one neuron per thread (128 neurons)
    const int jloc = tid * NBITS;
    const int jglob = x * JBLK + jloc;
    const double pw[NBITS] = {1.0, 2.0, 4.0, 8.0, 16.0, 32.0, 64.0, -128.0};
    double C = 0.0, pred = 0.0, ints = 0.0;
#pragma unroll
    for (int b = 0; b < NBITS; ++b) {
      const double Sb = S[jloc + b];
      const double ts = (double)true_sum[jglob + b];
      const double T  = Sb + C;
      const double c2 = floor(T * 0.5);
      C = c2;
      out[1 + jglob + b] = (float)((T - 2.0 * c2) - ts);
      pred += pw[b] * Sb;
      ints += pw[b] * ts;
    }
    const double d = pred - ints;
    err[tid] = d * d;
  }
  __syncthreads();

  // ---- Phase 3: group loss partial; globally-last finalizer writes loss ----
  if (tid == 0) {
    double e = 0.0;
#pragma unroll 16
    for (int k = 0; k < NEUR_PER_CB; ++k) e += err[k];
    lossp[x] = e;
    __threadfence();               // release lossp[x]
    if (atomicAdd(fin_ctr, 1) == NJB - 1) {
      __threadfence();             // acquire all lossp
      double t = 0.0;
#pragma unroll
      for (int k = 0; k < NJB; ++k) t += lossp[k];
      out[0] = (float)(t * (0.5 / (double)OUT_F));   // written exactly once
    }
  }
}

extern "C" void kernel_launch(void* const* d_in, const int* in_sizes, int n_in,
                              void* d_out, int out_size, void* d_ws, size_t ws_size,
                              hipStream_t stream) {
  const float* latent   = (const float*)d_in[0];   // [1, 4096]
  const float* true_sum = (const float*)d_in[1];   // [1, 8192]
  const float* w        = (const float*)d_in[2];   // [4096, 8192]
  float* out = (float*)d_out;                      // [1 + 8192]

  // ws layout: partials (64*8192 f32 = 2 MB) | lossp (8 f64) | ctr (8+1 i32)
  float*  partials = (float*)d_ws;
  double* lossp    = (double*)(partials + (size_t)NCHUNK * JTOT);
  int*    ctr      = (int*)(lossp + NJB);
  int*    fin_ctr  = ctr + NJB;

  hipMemsetAsync(ctr, 0, (NJB + 1) * sizeof(int), stream);  // zero tickets
  fused_kernel<<<dim3(NJB, NCHUNK), TB, 0, stream>>>(
      w, latent, true_sum, partials, lossp, ctr, fin_ctr, out);
}

// Round 7
// 191.523 us; speedup vs baseline: 1.4061x; 1.4061x over previous
//
#include <hip/hip_runtime.h>
#include <cmath>

// Problem constants (match reference)
#define IN_F   4096
#define OUT_F  1024
#define NBITS  8
#define JTOT   (OUT_F * NBITS)   // 8192 bit-columns
#define TB     256               // threads per block
#define CPT    4                 // columns per thread (float4 load)
#define JBLK   (TB * CPT)        // 1024 columns per block
#define NJB    (JTOT / JBLK)     // 8 column-blocks
#define ROWS   32                // rows per split-K chunk
#define NCHUNK (IN_F / ROWS)     // 128 chunks -> 1024 blocks (4/CU, latency hiding)

typedef float f32x4 __attribute__((ext_vector_type(4)));  // native vec for nontemporal builtin

// Kernel A: split-K column sums S[o,b] = sum_i latent[i] * (w[i, o*8+b] > 0.5)
// f32 chunk accumulation (32 adds of values < 1; abs err ~1e-5 in each chunk
// partial, far under the trigger tolerance). w is streamed with nontemporal
// loads (read-once). Block (0,0) zeroes the loss slot (stream order puts it
// before finalize's atomicAdd). No device fences anywhere — round 5 showed
// per-block __threadfence() costs ~80 us in TCC serialization.
__global__ __launch_bounds__(TB) void colsum_kernel(
    const float* __restrict__ w, const float* __restrict__ latent,
    float* __restrict__ partials, float* __restrict__ out) {
  const int j0 = (blockIdx.x * TB + threadIdx.x) * CPT;
  const int chunk = blockIdx.y;
  const int i0 = chunk * ROWS;
  if (blockIdx.x == 0 && blockIdx.y == 0 && threadIdx.x == 0) out[0] = 0.0f;

  float a0 = 0.f, a1 = 0.f, a2 = 0.f, a3 = 0.f;
  const f32x4* wp = reinterpret_cast<const f32x4*>(w + (size_t)i0 * JTOT + j0);
#pragma unroll
  for (int r = 0; r < ROWS; ++r) {
    const float lat = latent[i0 + r];                 // wave-uniform scalar load
    const f32x4 v = __builtin_nontemporal_load(wp + (size_t)r * (JTOT / 4));
    a0 += (v.x > 0.5f) ? lat : 0.0f;
    a1 += (v.y > 0.5f) ? lat : 0.0f;
    a2 += (v.z > 0.5f) ? lat : 0.0f;
    a3 += (v.w > 0.5f) ? lat : 0.0f;
  }
  f32x4 acc = {a0, a1, a2, a3};
  *reinterpret_cast<f32x4*>(partials + (size_t)chunk * JTOT + j0) = acc;
}

// Kernel B: reduce partials (f64) -> S_j; per neuron the exact closed-form
// ripple-carry result:
//   T_b = S_b + C_{b-1};  acc_b = T_b - 2*floor(T_b/2);  C_b = floor(T_b/2)
// trigger[o,b] = acc_b - true_sum[o*8+b]; pred[o] = sum_b pow_b * S_b;
// loss = 0.5/OUT_F * sum_o (pred - int_s)^2 accumulated via atomicAdd.
__global__ __launch_bounds__(TB) void finalize_kernel(
    const float* __restrict__ partials, const float* __restrict__ true_sum,
    float* __restrict__ out) {
  const int tid = threadIdx.x;
  const int j = blockIdx.x * TB + tid;   // 32 blocks cover 8192 columns
  double sA = 0.0, sB = 0.0;             // 2 accumulators to break the dep chain
#pragma unroll 8
  for (int c = 0; c < NCHUNK; c += 2) {
    sA += (double)partials[(size_t)c * JTOT + j];
    sB += (double)partials[(size_t)(c + 1) * JTOT + j];
  }
  const double s = sA + sB;

  __shared__ double S[TB];
  __shared__ double err[TB / NBITS];     // 32 neurons per block
  S[tid] = s;
  __syncthreads();

  if (tid < TB / NBITS) {
    const int o_local = tid;
    const int jbase = blockIdx.x * TB + o_local * NBITS;
    const double pw[NBITS] = {1.0, 2.0, 4.0, 8.0, 16.0, 32.0, 64.0, -128.0};
    double C = 0.0, pred = 0.0, ints = 0.0;
#pragma unroll
    for (int b = 0; b < NBITS; ++b) {
      const double Sb = S[o_local * NBITS + b];
      const double ts = (double)true_sum[jbase + b];
      const double T  = Sb + C;
      const double c2 = floor(T * 0.5);
      const double ab = T - 2.0 * c2;    // acc bit in [0,2)
      C = c2;
      out[1 + jbase + b] = (float)(ab - ts);
      pred += pw[b] * Sb;
      ints += pw[b] * ts;
    }
    const double d = pred - ints;
    err[o_local] = d * d;
  }
  __syncthreads();

  if (tid == 0) {
    double e = 0.0;
    for (int k = 0; k < TB / NBITS; ++k) e += err[k];
    atomicAdd(out, (float)(e * (0.5 / (double)OUT_F)));
  }
}

extern "C" void kernel_launch(void* const* d_in, const int* in_sizes, int n_in,
                              void* d_out, int out_size, void* d_ws, size_t ws_size,
                              hipStream_t stream) {
  const float* latent   = (const float*)d_in[0];   // [1, 4096]
  const float* true_sum = (const float*)d_in[1];   // [1, 8192]
  const float* w        = (const float*)d_in[2];   // [4096, 8192]
  float* out = (float*)d_out;                      // [1 + 8192]
  float* partials = (float*)d_ws;                  // 128*8192*4 = 4 MB << ws_size

  colsum_kernel<<<dim3(NJB, NCHUNK), TB, 0, stream>>>(w, latent, partials, out);
  finalize_kernel<<<dim3(JTOT / TB), TB, 0, stream>>>(partials, true_sum, out);
}